// Round 5
// baseline (122.292 us; speedup 1.0000x reference)
//
#include <hip/hip_runtime.h>

// LDDMM variational evolve: B=1, N=8192, D=3, fp32.
// dmom_i = 2g * (x_i * sum_j w_ij  -  sum_j w_ij x_j),  w_ij = K_ij <p_i,p_j>
// dx_i   = sum_j K_ij p_j,   K_ij = exp(-g |x_i - x_j|^2), g = 100.
//
// Round 8: DIAGNOSTIC round. partial has been ~40-45 us across 4 structural
// variants (LDS vs SMEM staging, ITILE 2/4, 4/8 blocks per CU, scalar vs
// v_pk_*) while every resource model says 13-20 us -- and its counters have
// never been visible because ~200 harness poison fills at ~48 us own the
// rocprof top-5. This round runs the j-loop a runtime `repeat`=2 times
// (accumulate 2S, scale 0.5 -> numerically equivalent; runtime bound so the
// compiler cannot fold it) to push partial to ~85 us = top-1 WITH counters.
// Config under test = best-known (ITILE=4, SEG=128, LDS broadcast staging).
// Decision tree on the counters is in the session journal.
// NOTE: ci must stay inside the exponent (arg <= 0 always); factoring
// exp2(ci) out overflows: inner arg reaches +432 -> inf * 0 = NaN.

#define TPB 256
#define ITILE 4
constexpr float GAMMA_C = 100.0f;
constexpr float LOG2E_C = 1.4426950408889634f;
constexpr float SB_C    = 2.0f * GAMMA_C * LOG2E_C;  // A.xyz = SB*x_j
constexpr float SC_C    = -GAMMA_C * LOG2E_C;        // A.w   = SC*|x_j|^2
constexpr float LN2_C   = 0.69314718055994531f;      // 2g/SB

// ---- Kernel A: per-segment partial sums ------------------------------------
// grid (N/(TPB*ITILE), SEG). part layout: P[c][s][i], c=0..6, each [SEG][N].
// `repeat` is a RUNTIME arg (launched with 2); `scale` = 1/repeat.
__global__ __launch_bounds__(TPB, 4) void lddmm_partial(
    const float* __restrict__ mom, const float* __restrict__ xpt,
    float* __restrict__ part, int N, int SEG, int JT,
    int repeat, float scale) {
  extern __shared__ float4 smem[];
  float4* sA = smem;        // {SB*x, SB*y, SB*z, SC*|x|^2}
  float4* sP = smem + JT;   // {px, py, pz, 0}
  const int tid = threadIdx.x;
  const int seg = blockIdx.y;

  for (int t = tid; t < JT; t += TPB) {
    const int j = seg * JT + t;
    const float bx = xpt[3*j], by = xpt[3*j+1], bz = xpt[3*j+2];
    sA[t] = make_float4(SB_C*bx, SB_C*by, SB_C*bz,
                        SC_C * fmaf(bx, bx, fmaf(by, by, bz*bz)));
    sP[t] = make_float4(mom[3*j], mom[3*j+1], mom[3*j+2], 0.f);
  }
  __syncthreads();

  const int i0 = blockIdx.x * (TPB * ITILE) + tid;

  float xi[ITILE], yi[ITILE], zi[ITILE];
  float px[ITILE], py[ITILE], pz[ITILE], ci[ITILE];
#pragma unroll
  for (int u = 0; u < ITILE; ++u) {
    const int i = i0 + u * TPB;
    xi[u] = xpt[3*i]; yi[u] = xpt[3*i+1]; zi[u] = xpt[3*i+2];
    px[u] = mom[3*i]; py[u] = mom[3*i+1]; pz[u] = mom[3*i+2];
    ci[u] = SC_C * fmaf(xi[u], xi[u], fmaf(yi[u], yi[u], zi[u]*zi[u]));
  }

  float a[ITILE], wx[ITILE], wy[ITILE], wz[ITILE];
  float gx[ITILE], gy[ITILE], gz[ITILE];
#pragma unroll
  for (int u = 0; u < ITILE; ++u) {
    a[u]=0.f; wx[u]=0.f; wy[u]=0.f; wz[u]=0.f;
    gx[u]=0.f; gy[u]=0.f; gz[u]=0.f;
  }

  for (int r = 0; r < repeat; ++r) {   // runtime bound: not foldable
#pragma unroll 2
    for (int t = 0; t < JT; ++t) {
      const float4 A = sA[t];   // broadcast (same addr all lanes)
      const float4 P = sP[t];
#pragma unroll
      for (int u = 0; u < ITILE; ++u) {
        const float arg = fmaf(A.x, xi[u],
                          fmaf(A.y, yi[u],
                          fmaf(A.z, zi[u], ci[u] + A.w)));
        const float K   = __builtin_amdgcn_exp2f(arg);   // bare v_exp_f32
        const float dot = fmaf(P.x, px[u], fmaf(P.y, py[u], P.z * pz[u]));
        const float w   = K * dot;
        a[u] += w;
        wx[u] = fmaf(w, A.x, wx[u]);
        wy[u] = fmaf(w, A.y, wy[u]);
        wz[u] = fmaf(w, A.z, wz[u]);
        gx[u] = fmaf(K, P.x, gx[u]);
        gy[u] = fmaf(K, P.y, gy[u]);
        gz[u] = fmaf(K, P.z, gz[u]);
      }
    }
  }

  const size_t SN = (size_t)SEG * N;
  float* p = part + (size_t)seg * N;
#pragma unroll
  for (int u = 0; u < ITILE; ++u) {
    const int i = i0 + u * TPB;
    p[0*SN+i] = a[u]  * scale;
    p[1*SN+i] = wx[u] * scale;
    p[2*SN+i] = wy[u] * scale;
    p[3*SN+i] = wz[u] * scale;
    p[4*SN+i] = gx[u] * scale;
    p[5*SN+i] = gy[u] * scale;
    p[6*SN+i] = gz[u] * scale;
  }
}

// ---- Kernel B: reduce over segments (parallel over channels) ---------------
__global__ __launch_bounds__(TPB) void lddmm_reduce(
    const float* __restrict__ part, float* __restrict__ R, int N, int SEG) {
  const int i = blockIdx.x * TPB + threadIdx.x;
  const int c = blockIdx.y;
  const float* src = part + (size_t)c * SEG * N + i;
  float s0 = 0.f, s1 = 0.f, s2 = 0.f, s3 = 0.f;
  int s = 0;
  for (; s + 4 <= SEG; s += 4) {
    s0 += src[(size_t)(s+0)*N]; s1 += src[(size_t)(s+1)*N];
    s2 += src[(size_t)(s+2)*N]; s3 += src[(size_t)(s+3)*N];
  }
  for (; s < SEG; ++s) s0 += src[(size_t)s*N];
  R[(size_t)c * N + i] = (s0 + s1) + (s2 + s3);
}

// ---- Kernel C: finalize ----------------------------------------------------
__global__ __launch_bounds__(TPB) void lddmm_finalize(
    const float* __restrict__ R, const float* __restrict__ xpt,
    float* __restrict__ out, int N) {
  const int i = blockIdx.x * TPB + threadIdx.x;
  const float A  = R[i];
  const float WX = R[(size_t)1*N+i], WY = R[(size_t)2*N+i], WZ = R[(size_t)3*N+i];
  const float GX = R[(size_t)4*N+i], GY = R[(size_t)5*N+i], GZ = R[(size_t)6*N+i];
  const float xi = xpt[3*i], yi = xpt[3*i+1], zi = xpt[3*i+2];
  const float TGA = 2.0f * GAMMA_C * A;
  out[3*i+0] = fmaf(TGA, xi, -LN2_C * WX);
  out[3*i+1] = fmaf(TGA, yi, -LN2_C * WY);
  out[3*i+2] = fmaf(TGA, zi, -LN2_C * WZ);
  out[3*N + 3*i + 0] = GX;
  out[3*N + 3*i + 1] = GY;
  out[3*N + 3*i + 2] = GZ;
}

// ---- Fallback (tiny ws): atomic single-kernel version ----------------------
__global__ __launch_bounds__(TPB) void lddmm_atomic(
    const float* __restrict__ mom, const float* __restrict__ xpt,
    float* __restrict__ out, int N) {
  const int i  = blockIdx.x * TPB + threadIdx.x;
  const int jb = blockIdx.y * TPB;
  __shared__ float4 sA[TPB], sP[TPB];
  {
    const int j = jb + threadIdx.x;
    const float bx = xpt[3*j], by = xpt[3*j+1], bz = xpt[3*j+2];
    sA[threadIdx.x] = make_float4(SB_C*bx, SB_C*by, SB_C*bz,
                                  SC_C * fmaf(bx, bx, fmaf(by, by, bz*bz)));
    sP[threadIdx.x] = make_float4(mom[3*j], mom[3*j+1], mom[3*j+2], 0.f);
  }
  __syncthreads();
  const float xi = xpt[3*i], yi = xpt[3*i+1], zi = xpt[3*i+2];
  const float pxi = mom[3*i], pyi = mom[3*i+1], pzi = mom[3*i+2];
  const float ci = SC_C * fmaf(xi, xi, fmaf(yi, yi, zi*zi));
  float a=0.f, wx=0.f, wy=0.f, wz=0.f, gx=0.f, gy=0.f, gz=0.f;
#pragma unroll 4
  for (int t = 0; t < TPB; ++t) {
    const float4 A = sA[t], P = sP[t];
    const float arg = fmaf(A.x, xi, fmaf(A.y, yi, fmaf(A.z, zi, ci + A.w)));
    const float K   = __builtin_amdgcn_exp2f(arg);
    const float dot = fmaf(P.x, pxi, fmaf(P.y, pyi, P.z * pzi));
    const float w   = K * dot;
    a += w;
    wx = fmaf(w, A.x, wx); wy = fmaf(w, A.y, wy); wz = fmaf(w, A.z, wz);
    gx = fmaf(K, P.x, gx); gy = fmaf(K, P.y, gy); gz = fmaf(K, P.z, gz);
  }
  const float TGA = 2.0f * GAMMA_C * a;
  atomicAdd(&out[3*i+0], fmaf(TGA, xi, -LN2_C * wx));
  atomicAdd(&out[3*i+1], fmaf(TGA, yi, -LN2_C * wy));
  atomicAdd(&out[3*i+2], fmaf(TGA, zi, -LN2_C * wz));
  atomicAdd(&out[3*N+3*i+0], gx);
  atomicAdd(&out[3*N+3*i+1], gy);
  atomicAdd(&out[3*N+3*i+2], gz);
}

extern "C" void kernel_launch(void* const* d_in, const int* in_sizes, int n_in,
                              void* d_out, int out_size, void* d_ws, size_t ws_size,
                              hipStream_t stream) {
  const float* mom = (const float*)d_in[0];   // setup_inputs order: mom first
  const float* xpt = (const float*)d_in[1];   // control_points second
  float* out = (float*)d_out;
  const int N = in_sizes[0] / 3;              // 8192

  // ws layout: part (7*SEG*N floats) | R (7*N floats)
  auto need = [&](int s) { return (size_t)(7*s + 7) * (size_t)N * sizeof(float); };
  int SEG = 128;
  while (SEG > 2 && need(SEG) > ws_size) SEG >>= 1;

  const bool shapes_ok = (N % (TPB * ITILE) == 0) && (N % SEG == 0) &&
                         ((N / SEG) <= TPB);
  if (need(SEG) <= ws_size && shapes_ok) {
    const int JT = N / SEG;                   // 64 @ SEG=128
    float* partb = (float*)d_ws;
    float* R     = partb + (size_t)7 * SEG * N;
    const size_t shmem = (size_t)JT * 2 * sizeof(float4);
    dim3 gA(N / (TPB * ITILE), SEG);          // (8, 128) = 1024 blocks, 4/CU
    // DIAGNOSTIC: repeat=2 (runtime), scale=0.5f -> partial ~2x duration so
    // it surfaces above the ~48us poison fills in the rocprof top-5.
    lddmm_partial<<<gA, TPB, shmem, stream>>>(mom, xpt, partb, N, SEG, JT,
                                              2, 0.5f);
    dim3 gB(N / TPB, 7);                      // 224 blocks — parallel reduce
    lddmm_reduce<<<gB, TPB, 0, stream>>>(partb, R, N, SEG);
    lddmm_finalize<<<N / TPB, TPB, 0, stream>>>(R, xpt, out, N);
  } else {
    hipMemsetAsync(d_out, 0, (size_t)out_size * sizeof(float), stream);
    dim3 grid(N / TPB, N / TPB);
    lddmm_atomic<<<grid, TPB, 0, stream>>>(mom, xpt, out, N);
  }
}